// Round 2
// baseline (375.213 us; speedup 1.0000x reference)
//
#include <hip/hip_runtime.h>
#include <cstdint>
#include <cstddef>

typedef _Float16 half_t;
typedef _Float16 half8 __attribute__((ext_vector_type(8)));
typedef _Float16 half4v __attribute__((ext_vector_type(4)));
typedef float float4_ __attribute__((ext_vector_type(4)));

#define NB 8
#define SEQ 2048
#define DIM 256
#define NROWS (NB*SEQ)   // 16384

// ---------------------------------------------------------------------------
// Kernel 1: fold Wc = Wa @ Wk, bc = Wa @ bk + ba; split weights to fp16 hi/lo
// ---------------------------------------------------------------------------
__global__ __launch_bounds__(256) void prep_kernel(
    const float* __restrict__ Wq, const float* __restrict__ Wk,
    const float* __restrict__ Wv, const float* __restrict__ Wa,
    const float* __restrict__ bk, const float* __restrict__ ba,
    half_t* __restrict__ Wq_hi, half_t* __restrict__ Wq_lo,
    half_t* __restrict__ Wc_hi, half_t* __restrict__ Wc_lo,
    half_t* __restrict__ Wv_hi, float* __restrict__ bc)
{
    const int e = blockIdx.x;
    const int d = threadIdx.x;
    const int idx = e * 256 + d;
    float acc = 0.f;
    for (int m = 0; m < 256; ++m)
        acc += Wa[e * 256 + m] * Wk[m * 256 + d];
    half_t h = (half_t)acc;
    Wc_hi[idx] = h;
    Wc_lo[idx] = (half_t)(acc - (float)h);
    float wq = Wq[idx];
    h = (half_t)wq;
    Wq_hi[idx] = h;
    Wq_lo[idx] = (half_t)(wq - (float)h);
    Wv_hi[idx] = (half_t)Wv[idx];
    if (d == 0) {
        float bacc = ba[e];
        for (int m = 0; m < 256; ++m) bacc += Wa[e * 256 + m] * bk[m];
        bc[e] = bacc;
    }
}

// ---------------------------------------------------------------------------
// Kernel 2: linears. seg0: q = x@Wq^T+bq (hi/lo). seg1: wk = states@Wc^T+bc
// (hi/lo). seg2: v = states@Wv^T+bv -> vT[b][d][s] (hi only).
// Block: 256 thr / 4 waves, 64 rows/block. fp16x3 split MFMA.
// ---------------------------------------------------------------------------
__global__ __launch_bounds__(256) void linear_kernel(
    const float* __restrict__ x, const float* __restrict__ states,
    const half_t* __restrict__ Wq_hi, const half_t* __restrict__ Wq_lo, const float* __restrict__ bq,
    const half_t* __restrict__ Wc_hi, const half_t* __restrict__ Wc_lo, const float* __restrict__ bc,
    const half_t* __restrict__ Wv_hi, const float* __restrict__ bv,
    half_t* __restrict__ q_hi, half_t* __restrict__ q_lo,
    half_t* __restrict__ wk_hi, half_t* __restrict__ wk_lo,
    half_t* __restrict__ vT)
{
    __shared__ half_t lds[2 * 64 * 256];   // A_hi [64][256], A_lo [64][256]  (64 KiB)
    half_t* A_hi = lds;
    half_t* A_lo = lds + 64 * 256;

    const int seg  = blockIdx.x >> 8;      // 0:q 1:wk 2:v
    const int t    = blockIdx.x & 255;
    const int tid  = threadIdx.x;
    const int lane = tid & 63;
    const int wv   = tid >> 6;
    const int quad = lane >> 4;
    const int l15  = lane & 15;
    const int r0   = t * 64;               // global row base (rows = b*2048+s)

    const float* src  = (seg == 0) ? x : states;
    const half_t* Bh  = (seg == 0) ? Wq_hi : (seg == 1) ? Wc_hi : Wv_hi;
    const half_t* Bl  = (seg == 0) ? Wq_lo : Wc_lo;   // unused for seg 2
    const float* bias = (seg == 0) ? bq : (seg == 1) ? bc : bv;

    // stage A tile: 64 rows x 256 f32 -> hi/lo fp16 planes in LDS
    for (int i = 0; i < 16; ++i) {
        int f4 = tid + i * 256;                        // 0..4095 float4s
        int row = f4 >> 6, col = (f4 & 63) << 2;
        float4_ v = *(const float4_*)(src + (size_t)(r0 + row) * 256 + col);
        half4v h, l;
        #pragma unroll
        for (int j = 0; j < 4; ++j) {
            half_t hh = (half_t)v[j];
            h[j] = hh;
            l[j] = (half_t)(v[j] - (float)hh);
        }
        *(half4v*)(A_hi + row * 256 + col) = h;
        if (seg != 2) *(half4v*)(A_lo + row * 256 + col) = l;
    }
    __syncthreads();

    // preload A fragments: 8 d-chunks x {hi,lo}
    half8 ah[8], al[8];
    #pragma unroll
    for (int c = 0; c < 8; ++c) {
        ah[c] = *(const half8*)(A_hi + (wv * 16 + l15) * 256 + c * 32 + quad * 8);
        if (seg != 2)
            al[c] = *(const half8*)(A_lo + (wv * 16 + l15) * 256 + c * 32 + quad * 8);
    }

    float4_ acc[16];
    #pragma unroll
    for (int nt = 0; nt < 16; ++nt) {
        float4_ a = {0.f, 0.f, 0.f, 0.f};
        #pragma unroll
        for (int c = 0; c < 8; ++c) {
            half8 bhf = *(const half8*)(Bh + (size_t)(nt * 16 + l15) * 256 + c * 32 + quad * 8);
            a = __builtin_amdgcn_mfma_f32_16x16x32_f16(ah[c], bhf, a, 0, 0, 0);
            if (seg != 2) {
                half8 blf = *(const half8*)(Bl + (size_t)(nt * 16 + l15) * 256 + c * 32 + quad * 8);
                a = __builtin_amdgcn_mfma_f32_16x16x32_f16(al[c], bhf, a, 0, 0, 0);
                a = __builtin_amdgcn_mfma_f32_16x16x32_f16(ah[c], blf, a, 0, 0, 0);
            }
        }
        float be = bias[nt * 16 + l15];
        a[0] += be; a[1] += be; a[2] += be; a[3] += be;
        acc[nt] = a;
    }

    // epilogue: repack through LDS (reuse A_hi region) for coalesced stores
    half_t* R = A_hi;
    __syncthreads();   // all waves done with A-frag preloads
    #pragma unroll
    for (int nt = 0; nt < 16; ++nt)
        #pragma unroll
        for (int r = 0; r < 4; ++r)
            R[(wv * 16 + quad * 4 + r) * 256 + nt * 16 + l15] = (half_t)acc[nt][r];
    __syncthreads();

    if (seg != 2) {
        half_t* dst_hi = (seg == 0) ? q_hi : wk_hi;
        // 64 rows x 32 chunks of 8 halfs = 2048 chunks -> 8 iterations (NOT 16!)
        for (int i = 0; i < 8; ++i) {
            int g = tid + i * 256;                 // 16B chunks, 0..2047
            int row = g >> 5, cc = g & 31;
            *(half8*)(dst_hi + (size_t)(r0 + row) * 256 + cc * 8) =
                *(const half8*)(R + row * 256 + cc * 8);
        }
        __syncthreads();
        #pragma unroll
        for (int nt = 0; nt < 16; ++nt)
            #pragma unroll
            for (int r = 0; r < 4; ++r) {
                float v = acc[nt][r];
                half_t hh = (half_t)v;
                R[(wv * 16 + quad * 4 + r) * 256 + nt * 16 + l15] = (half_t)(v - (float)hh);
            }
        __syncthreads();
        half_t* dst_lo = (seg == 0) ? q_lo : wk_lo;
        for (int i = 0; i < 8; ++i) {
            int g = tid + i * 256;                 // 0..2047
            int row = g >> 5, cc = g & 31;
            *(half8*)(dst_lo + (size_t)(r0 + row) * 256 + cc * 8) =
                *(const half8*)(R + row * 256 + cc * 8);
        }
    } else {
        // transpose: vT[b][d][s0+..]
        const int b = r0 >> 11, s0 = r0 & 2047;
        const int d = tid;
        for (int sc = 0; sc < 8; ++sc) {
            half8 pack;
            #pragma unroll
            for (int j = 0; j < 8; ++j) pack[j] = R[(sc * 8 + j) * 256 + d];
            *(half8*)(vT + ((size_t)b * 256 + d) * 2048 + s0 + sc * 8) = pack;
        }
    }
}

// ---------------------------------------------------------------------------
// Kernel 3: flash attention. 256 blocks (b = blk&7 for XCD locality), 4 waves
// x 16 q-rows, Nk=32 k-tiles. S = q.wk^T via fp16x3 MFMA; online softmax;
// ctx += P.V via fp16 MFMA with vT B-frags. LDS chunk-XOR-swizzled.
// ---------------------------------------------------------------------------
__global__ __launch_bounds__(256) void attn_kernel(
    const half_t* __restrict__ q_hi, const half_t* __restrict__ q_lo,
    const half_t* __restrict__ wk_hi, const half_t* __restrict__ wk_lo,
    const half_t* __restrict__ vT, float* __restrict__ out)
{
    __shared__ half_t s_wk_hi[32 * 256];   // [s' 0..31][chunk-slot 0..31][8]
    __shared__ half_t s_wk_lo[32 * 256];
    __shared__ half_t s_vt[256 * 32];      // [d 0..255][chunk-slot 0..3][8]
    __shared__ half_t s_p[4][16 * 48];     // per-wave P tile, padded stride 48

    const int tid  = threadIdx.x;
    const int lane = tid & 63;
    const int wv   = tid >> 6;
    const int quad = lane >> 4;
    const int l15  = lane & 15;

    const int b    = blockIdx.x & 7;       // XCD-swizzle: batch per XCD
    const int tile = blockIdx.x >> 3;      // 0..31

    // q fragments resident in registers: rows = tile*64 + wv*16 + l15
    const size_t qrow = (size_t)b * 2048 + tile * 64 + wv * 16 + l15;
    half8 qh[8], ql[8];
    #pragma unroll
    for (int c = 0; c < 8; ++c) {
        qh[c] = *(const half8*)(q_hi + qrow * 256 + c * 32 + quad * 8);
        ql[c] = *(const half8*)(q_lo + qrow * 256 + c * 32 + quad * 8);
    }

    float4_ ctx[16];
    #pragma unroll
    for (int i = 0; i < 16; ++i) ctx[i] = {0.f, 0.f, 0.f, 0.f};
    float m_r[4] = {-1e30f, -1e30f, -1e30f, -1e30f};
    float l_r[4] = {0.f, 0.f, 0.f, 0.f};

    const half_t* wkh_b = wk_hi + (size_t)b * 2048 * 256;
    const half_t* wkl_b = wk_lo + (size_t)b * 2048 * 256;
    const half_t* vt_b  = vT + (size_t)b * 256 * 2048;

    for (int kt = 0; kt < 64; ++kt) {
        const int k0 = kt * 32;
        __syncthreads();   // previous iteration's LDS reads complete
        // stage wk_hi / wk_lo tiles [32 s' x 256 d], XOR-swizzled chunks
        #pragma unroll
        for (int i = 0; i < 4; ++i) {
            int g = tid + i * 256;             // 0..1023 chunks
            int s = g >> 5, c = g & 31;
            half8 v1 = *(const half8*)(wkh_b + (size_t)(k0 + s) * 256 + c * 8);
            *(half8*)(s_wk_hi + s * 256 + ((c ^ (s & 7)) * 8)) = v1;
        }
        #pragma unroll
        for (int i = 0; i < 4; ++i) {
            int g = tid + i * 256;
            int s = g >> 5, c = g & 31;
            half8 v1 = *(const half8*)(wkl_b + (size_t)(k0 + s) * 256 + c * 8);
            *(half8*)(s_wk_lo + s * 256 + ((c ^ (s & 7)) * 8)) = v1;
        }
        // stage vT tile [256 d x 32 s]
        #pragma unroll
        for (int i = 0; i < 4; ++i) {
            int g = tid + i * 256;
            int d = g >> 2, sc = g & 3;
            half8 v1 = *(const half8*)(vt_b + (size_t)d * 2048 + k0 + sc * 8);
            *(half8*)(s_vt + d * 32 + ((sc ^ (d & 3)) * 8)) = v1;
        }
        __syncthreads();

        // S = q . wk^T : 2 n-tiles of 16 cols, fp16x3 split
        float4_ S[2];
        #pragma unroll
        for (int nt = 0; nt < 2; ++nt) {
            float4_ a = {0.f, 0.f, 0.f, 0.f};
            const int srow = nt * 16 + l15;
            #pragma unroll
            for (int c = 0; c < 8; ++c) {
                const int gc = c * 4 + quad;
                const int slot = (gc ^ (srow & 7)) * 8;
                half8 bhf = *(const half8*)(s_wk_hi + srow * 256 + slot);
                half8 blf = *(const half8*)(s_wk_lo + srow * 256 + slot);
                a = __builtin_amdgcn_mfma_f32_16x16x32_f16(qh[c], bhf, a, 0, 0, 0);
                a = __builtin_amdgcn_mfma_f32_16x16x32_f16(ql[c], bhf, a, 0, 0, 0);
                a = __builtin_amdgcn_mfma_f32_16x16x32_f16(qh[c], blf, a, 0, 0, 0);
            }
            S[nt] = a;
        }

        // online softmax update (row = quad*4 + r, cols across 16 lanes x 2 nt)
        float alpha[4], p0[4], p1[4];
        #pragma unroll
        for (int r = 0; r < 4; ++r) {
            float mx = fmaxf(S[0][r], S[1][r]);
            mx = fmaxf(mx, __shfl_xor(mx, 1, 16));
            mx = fmaxf(mx, __shfl_xor(mx, 2, 16));
            mx = fmaxf(mx, __shfl_xor(mx, 4, 16));
            mx = fmaxf(mx, __shfl_xor(mx, 8, 16));
            float mnew = fmaxf(m_r[r], mx);
            alpha[r] = __expf(m_r[r] - mnew);
            p0[r] = __expf(S[0][r] - mnew);
            p1[r] = __expf(S[1][r] - mnew);
            float rs = p0[r] + p1[r];
            rs += __shfl_xor(rs, 1, 16);
            rs += __shfl_xor(rs, 2, 16);
            rs += __shfl_xor(rs, 4, 16);
            rs += __shfl_xor(rs, 8, 16);
            l_r[r] = l_r[r] * alpha[r] + rs;
            m_r[r] = mnew;
        }
        #pragma unroll
        for (int i = 0; i < 16; ++i) {
            ctx[i][0] *= alpha[0];
            ctx[i][1] *= alpha[1];
            ctx[i][2] *= alpha[2];
            ctx[i][3] *= alpha[3];
        }

        // P -> LDS (wave-private) into A-operand layout
        #pragma unroll
        for (int r = 0; r < 4; ++r) {
            s_p[wv][(quad * 4 + r) * 48 + l15]      = (half_t)p0[r];
            s_p[wv][(quad * 4 + r) * 48 + 16 + l15] = (half_t)p1[r];
        }
        half8 pf = *(const half8*)(&s_p[wv][l15 * 48 + quad * 8]);

        // ctx += P @ V  (B-frags from transposed vT tile)
        #pragma unroll
        for (int nt2 = 0; nt2 < 16; ++nt2) {
            const int d = nt2 * 16 + l15;
            half8 vf = *(const half8*)(s_vt + d * 32 + ((quad ^ (d & 3)) * 8));
            ctx[nt2] = __builtin_amdgcn_mfma_f32_16x16x32_f16(pf, vf, ctx[nt2], 0, 0, 0);
        }
    }

    // epilogue: out = ctx / l
    const size_t orow_base = (size_t)b * 2048 + tile * 64 + wv * 16;
    #pragma unroll
    for (int nt2 = 0; nt2 < 16; ++nt2) {
        #pragma unroll
        for (int r = 0; r < 4; ++r) {
            const size_t row = orow_base + quad * 4 + r;
            out[row * 256 + nt2 * 16 + l15] = ctx[nt2][r] / l_r[r];
        }
    }
}

// ---------------------------------------------------------------------------
extern "C" void kernel_launch(void* const* d_in, const int* in_sizes, int n_in,
                              void* d_out, int out_size, void* d_ws, size_t ws_size,
                              hipStream_t stream) {
    const float* x      = (const float*)d_in[0];
    const float* states = (const float*)d_in[1];
    const float* Wq     = (const float*)d_in[2];
    const float* bq     = (const float*)d_in[3];
    const float* Wk     = (const float*)d_in[4];
    const float* bk     = (const float*)d_in[5];
    const float* Wv     = (const float*)d_in[6];
    const float* bv     = (const float*)d_in[7];
    const float* Wa     = (const float*)d_in[8];
    const float* ba     = (const float*)d_in[9];
    float* out = (float*)d_out;

    char* ws = (char*)d_ws;
    size_t off = 0;
    auto alloc = [&](size_t bytes) -> void* {
        void* p = ws + off;
        off += (bytes + 255) & ~(size_t)255;
        return p;
    };
    half_t* Wq_hi = (half_t*)alloc(65536 * 2);
    half_t* Wq_lo = (half_t*)alloc(65536 * 2);
    half_t* Wc_hi = (half_t*)alloc(65536 * 2);
    half_t* Wc_lo = (half_t*)alloc(65536 * 2);
    half_t* Wv_hi = (half_t*)alloc(65536 * 2);
    float*  bc    = (float*)alloc(256 * 4);
    half_t* q_hi  = (half_t*)alloc((size_t)NROWS * 256 * 2);
    half_t* q_lo  = (half_t*)alloc((size_t)NROWS * 256 * 2);
    half_t* wk_hi = (half_t*)alloc((size_t)NROWS * 256 * 2);
    half_t* wk_lo = (half_t*)alloc((size_t)NROWS * 256 * 2);
    half_t* vT    = (half_t*)alloc((size_t)NROWS * 256 * 2);

    prep_kernel<<<256, 256, 0, stream>>>(Wq, Wk, Wv, Wa, bk, ba,
                                         Wq_hi, Wq_lo, Wc_hi, Wc_lo, Wv_hi, bc);
    linear_kernel<<<768, 256, 0, stream>>>(x, states,
                                           Wq_hi, Wq_lo, bq,
                                           Wc_hi, Wc_lo, bc,
                                           Wv_hi, bv,
                                           q_hi, q_lo, wk_hi, wk_lo, vT);
    attn_kernel<<<256, 256, 0, stream>>>(q_hi, q_lo, wk_hi, wk_lo, vT, out);
}